// Round 1
// baseline (2098.646 us; speedup 1.0000x reference)
//
#include <hip/hip_runtime.h>
#include <hip/hip_bf16.h>
#include <hip/hip_cooperative_groups.h>

#define BB 8
#define NN 2048
#define DD 128
#define NSTEPS 16
#define DT_F 0.1f
#define TWO_PI_F 6.283185307179586f

namespace cg = cooperative_groups;

typedef short short8 __attribute__((ext_vector_type(8)));
typedef float floatx4 __attribute__((ext_vector_type(4)));

// ---------------- K0: split fp32 embeddings into bf16 hi/lo ----------------
__global__ void split_kernel(const float* __restrict__ e,
                             __hip_bfloat16* __restrict__ hi,
                             __hip_bfloat16* __restrict__ lo) {
    int i = blockIdx.x * 256 + threadIdx.x;
    float x = e[i];
    __hip_bfloat16 h = __float2bfloat16(x);
    hi[i] = h;
    lo[i] = __float2bfloat16(x - __bfloat162float(h));
}

// ---------------- K1: coupling matrix via bf16 MFMA (hi/lo split) ----------
// exp(-acosh(x)) = 1/(x + sqrt(x^2-1)); /1.000001 tau factor <=1e-5 rel.
#define LDP 136

__launch_bounds__(256, 2)
__global__ void coupling_kernel(const __hip_bfloat16* __restrict__ Ehi,
                                const __hip_bfloat16* __restrict__ Elo,
                                __hip_bfloat16* __restrict__ C) {
    __shared__ __hip_bfloat16 Ah[64 * LDP];
    __shared__ __hip_bfloat16 Al[64 * LDP];
    __shared__ __hip_bfloat16 Bh[64 * LDP];
    __shared__ __hip_bfloat16 Bl[64 * LDP];

    const int b  = blockIdx.z;
    const int n0 = blockIdx.y * 64;
    const int m0 = blockIdx.x * 64;
    const int tid = threadIdx.x;

    const __hip_bfloat16* aHsrc = Ehi + ((size_t)b * NN + n0) * DD;
    const __hip_bfloat16* aLsrc = Elo + ((size_t)b * NN + n0) * DD;
    const __hip_bfloat16* bHsrc = Ehi + ((size_t)b * NN + m0) * DD;
    const __hip_bfloat16* bLsrc = Elo + ((size_t)b * NN + m0) * DD;

    #pragma unroll
    for (int i = 0; i < 4; ++i) {
        int c   = tid + 256 * i;
        int row = c >> 4;
        int col = (c & 15) * 8;
        *(uint4*)(Ah + row * LDP + col) = *(const uint4*)(aHsrc + row * DD + col);
        *(uint4*)(Al + row * LDP + col) = *(const uint4*)(aLsrc + row * DD + col);
        *(uint4*)(Bh + row * LDP + col) = *(const uint4*)(bHsrc + row * DD + col);
        *(uint4*)(Bl + row * LDP + col) = *(const uint4*)(bLsrc + row * DD + col);
    }
    __syncthreads();

    const int wave = tid >> 6;
    const int lane = tid & 63;
    const int l16  = lane & 15;
    const int quad = lane >> 4;

    floatx4 acc[4] = {floatx4{0,0,0,0}, floatx4{0,0,0,0},
                      floatx4{0,0,0,0}, floatx4{0,0,0,0}};

    const int arow = wave * 16 + l16;
    #pragma unroll
    for (int kt = 0; kt < 4; ++kt) {
        const int ko = kt * 32 + quad * 8;
        short8 ah = *(const short8*)(Ah + arow * LDP + ko);
        short8 al = *(const short8*)(Al + arow * LDP + ko);
        #pragma unroll
        for (int c = 0; c < 4; ++c) {
            const int brow = c * 16 + l16;
            short8 bh = *(const short8*)(Bh + brow * LDP + ko);
            short8 bl = *(const short8*)(Bl + brow * LDP + ko);
            acc[c] = __builtin_amdgcn_mfma_f32_16x16x32_bf16(ah, bh, acc[c], 0, 0, 0);
            acc[c] = __builtin_amdgcn_mfma_f32_16x16x32_bf16(ah, bl, acc[c], 0, 0, 0);
            acc[c] = __builtin_amdgcn_mfma_f32_16x16x32_bf16(al, bh, acc[c], 0, 0, 0);
        }
    }

    float tn2[4];
    #pragma unroll
    for (int i = 0; i < 4; ++i) {
        int r = wave * 16 + quad * 4 + i;
        tn2[i] = 2.0f * (__bfloat162float(Ah[r * LDP]) + __bfloat162float(Al[r * LDP]));
    }
    #pragma unroll
    for (int c = 0; c < 4; ++c) {
        int br = c * 16 + l16;
        float tm = __bfloat162float(Bh[br * LDP]) + __bfloat162float(Bl[br * LDP]);
        size_t base = ((size_t)b * NN + n0 + wave * 16 + quad * 4) * (size_t)NN
                      + m0 + c * 16 + l16;
        #pragma unroll
        for (int i = 0; i < 4; ++i) {
            float g   = acc[c][i];
            float arg = fmaxf(fmaf(tn2[i], tm, -g), 1.0f + 1e-7f);
            float s   = sqrtf(fmaf(arg, arg, -1.0f));
            float cp  = __builtin_amdgcn_rcpf(arg + s);
            C[base + (size_t)i * NN] = __float2bfloat16(fminf(cp, 1.0f));
        }
    }
}

// ---------------- K2: persistent cooperative kernel — all 16 steps ---------
// 256 blocks (1/CU) x 512 threads (8 waves, 2/SIMD). Each wave owns 8 rows of
// C held ENTIRELY in registers (8 rows x 32 bf16/lane = 128 VGPRs). C is read
// from global exactly once; each step is pure VALU + one grid sync.
// Numerics identical to previous per-step kernel (same per-lane column map,
// same shuffle-reduce order, same update formula).

#define CSPAD(m) ((m) + ((m) >> 3))   // +1 float2 pad per 8: lane stride 72B

__launch_bounds__(512, 2)
__global__ void persist_kernel(const __hip_bfloat16* __restrict__ C,
                               const float* __restrict__ theta0,
                               float* __restrict__ thA,
                               float* __restrict__ thB,
                               float* __restrict__ outp,
                               const float* __restrict__ omega) {
    __shared__ float2 cs[NN + (NN >> 3)];   // 2304 float2 = 18 KiB

    const int tid  = threadIdx.x;
    const int lane = tid & 63;
    const int wave = tid >> 6;              // 0..7
    const int b    = blockIdx.x >> 5;       // batch
    const int rg   = blockIdx.x & 31;       // row group within batch
    const int row0 = rg * 64 + wave * 8;    // first of this wave's 8 rows

    // ---- load this wave's 8 C-rows into registers (coalesced 1KB/instr) ----
    uint4 creg[8][4];
    {
        const __hip_bfloat16* Cw = C + ((size_t)b * NN + row0) * (size_t)NN + lane * 8;
        #pragma unroll
        for (int r = 0; r < 8; ++r) {
            #pragma unroll
            for (int j = 0; j < 4; ++j)
                creg[r][j] = *(const uint4*)(Cw + (size_t)r * NN + j * 512);
        }
    }

    cg::grid_group grid = cg::this_grid();

    const float* cur = theta0;
    for (int s = 0; s < NSTEPS; ++s) {
        const float* th_b = cur + b * NN;

        // ---- cos/sin table for this batch's 2048 thetas (padded LDS) ----
        #pragma unroll
        for (int i = 0; i < 4; ++i) {
            int m = tid + 512 * i;
            float sv, cv;
            __sincosf(th_b[m], &sv, &cv);
            cs[CSPAD(m)] = make_float2(cv, sv);
        }
        __syncthreads();

        // ---- per-lane cc/ss register cache (reused across 8 rows) ----
        float cc[32], ss[32];
        #pragma unroll
        for (int j = 0; j < 4; ++j) {
            int p0 = CSPAD(j * 512 + lane * 8);
            #pragma unroll
            for (int i = 0; i < 8; ++i) {
                float2 v = cs[p0 + i];
                cc[j * 8 + i] = v.x;
                ss[j * 8 + i] = v.y;
            }
        }

        // ---- MAC: 8 rows x 32 elements, C from registers ----
        float sumc[8], sums[8];
        #pragma unroll
        for (int r = 0; r < 8; ++r) {
            float a0 = 0.f, a1 = 0.f, s0 = 0.f, s1 = 0.f;
            #pragma unroll
            for (int j = 0; j < 4; ++j) {
                unsigned u[4] = {creg[r][j].x, creg[r][j].y, creg[r][j].z, creg[r][j].w};
                #pragma unroll
                for (int k = 0; k < 4; ++k) {
                    float f0 = __uint_as_float(u[k] << 16);
                    float f1 = __uint_as_float(u[k] & 0xffff0000u);
                    int idx = j * 8 + 2 * k;
                    a0 = fmaf(f0, cc[idx],     a0);
                    s0 = fmaf(f0, ss[idx],     s0);
                    a1 = fmaf(f1, cc[idx + 1], a1);
                    s1 = fmaf(f1, ss[idx + 1], s1);
                }
            }
            sumc[r] = a0 + a1;
            sums[r] = s0 + s1;
        }

        // ---- 64-lane butterfly reduce (same order as before) ----
        #pragma unroll
        for (int r = 0; r < 8; ++r) {
            #pragma unroll
            for (int off = 32; off >= 1; off >>= 1) {
                sumc[r] += __shfl_xor(sumc[r], off, 64);
                sums[r] += __shfl_xor(sums[r], off, 64);
            }
        }

        // ---- theta update for this wave's 8 rows ----
        float* nxt = (s == NSTEPS - 1) ? outp : ((s & 1) ? thB : thA);
        #pragma unroll
        for (int r = 0; r < 8; ++r) {
            if (lane == r) {
                int n = row0 + r;
                float2 csn = cs[CSPAD(n)];
                float sum  = csn.y * sumc[r] - csn.x * sums[r];
                float th   = th_b[n];
                float dth  = omega[n] + (1.0f / NN) * sum;
                nxt[b * NN + n] = fmodf(th + DT_F * dth, TWO_PI_F);
            }
        }

        if (s != NSTEPS - 1) {
            __threadfence();     // release own theta writes device-wide
            grid.sync();         // all blocks' writes done
            __threadfence();     // acquire: invalidate stale cached theta
            cur = (s & 1) ? thB : thA;
        }
    }
}

// ---------------- launch ----------------------------------------------------
extern "C" void kernel_launch(void* const* d_in, const int* in_sizes, int n_in,
                              void* d_out, int out_size, void* d_ws, size_t ws_size,
                              hipStream_t stream) {
    const float* theta0 = (const float*)d_in[0];
    const float* emb    = (const float*)d_in[1];
    const float* omega  = (const float*)d_in[2];
    float* out = (float*)d_out;

    char* ws = (char*)d_ws;
    __hip_bfloat16* C   = (__hip_bfloat16*)ws;                       // 64 MiB
    __hip_bfloat16* Ehi = (__hip_bfloat16*)(ws + 67108864);          // 4 MiB
    __hip_bfloat16* Elo = (__hip_bfloat16*)(ws + 71303168);          // 4 MiB
    float* tA = (float*)(ws + 75497472);                             // 64 KiB
    float* tB = (float*)(ws + 75563008);                             // 64 KiB

    split_kernel<<<(BB * NN * DD) / 256, 256, 0, stream>>>(emb, Ehi, Elo);

    dim3 g1(NN / 64, NN / 64, BB);
    coupling_kernel<<<g1, 256, 0, stream>>>(Ehi, Elo, C);

    const __hip_bfloat16* Cc = C;
    void* kargs[] = { (void*)&Cc, (void*)&theta0, (void*)&tA, (void*)&tB,
                      (void*)&out, (void*)&omega };
    hipLaunchCooperativeKernel((void*)persist_kernel,
                               dim3(BB * (NN / 64)), dim3(512),
                               kargs, 0, stream);
}